// Round 2
// 398.270 us; speedup vs baseline: 1.1725x; 1.1725x over previous
//
#include <hip/hip_runtime.h>
#include <stdint.h>

// Problem: KS=3, ST=2, PAD=1, H=W=28, C=768, NH=12, hh=ww=14, dh=64.
//
// R4 theory: R3 kernel had VGPR_Count=12 -> one float4 load in flight,
// fully latency-serialized (VALUBusy 8%, HBM 11%, both pipes idle).
// Restructure to the distinct-tap formulation:
//   out[b,y,x,c] = sum_{dy,dx} cf[dy][dx] * vvpad[y+dy, x+dx, c]
//   cf[dy][dx]   = sum over contributing (kh,kw) combos of
//                  attn[b,h,w,n, 3kh+kw, 3(dy+kh)+(dx+kw)]
// where the combo set is determined by the parity of (y+1, x+1):
//   ypad odd  -> kh=1 only          -> dy in [-1,1]  (3 rows)
//   ypad even -> kh in {0,2}        -> dy in [-2,2]  (5 rows)
// (kh=0 additionally requires y<=25; same for x.)
// Parity is uniform per block -> 4 fully-static template paths; every tap
// load is unconditional (clamped addr, coefficient zeroed for OOB) so the
// compiler can issue ALL 9..25 float4 loads before any FMA consumes them.
//
// R5 fix: in_sizes[] is ELEMENT count, not bytes -- R4 divided by an extra
// 4, launching only 16 of 64 images (absmax 42 = untouched memset-0 output).
// Device code unchanged.
#define HOUT 28
#define HH   14
#define NHEADS 12
#define CC   768
#define NPIX (HOUT * HOUT)   // 784

// Accumulate one (kh,kw) combo's 9 attn values into the coefficient grid.
// All indices compile-time -> cf stays in registers.
template<int KH, int KW, int DY0, int DX0, int NY, int NX>
__device__ __forceinline__ void addTap(float (&cf)[NY][NX],
                                       const float* __restrict__ ab,
                                       int ypad, int xpad)
{
    const int h = (ypad - KH) >> 1;
    const int w = (xpad - KW) >> 1;
    // attn[b,h,w,n,p,q]; ab already includes b and n offsets.
    const float* ap = ab + (size_t)(h * HH + w) * (NHEADS * 81)
                         + (KH * 3 + KW) * 9;
    #pragma unroll
    for (int qh = 0; qh < 3; ++qh)
        #pragma unroll
        for (int qw = 0; qw < 3; ++qw)
            cf[qh - KH - DY0][qw - KW - DX0] += ap[3 * qh + qw];
}

// YE/XE: ypad/xpad even (5-wide neighborhood) vs odd (3-wide).
template<bool YE, bool XE>
__device__ __forceinline__ float4 process(const float* __restrict__ vb,
                                          const float* __restrict__ ab,
                                          int y, int x)
{
    constexpr int NY  = YE ? 5 : 3;
    constexpr int NX  = XE ? 5 : 3;
    constexpr int DY0 = YE ? -2 : -1;
    constexpr int DX0 = XE ? -2 : -1;

    // ---- Phase 1: issue ALL vv tap loads (independent, clamped). ----
    float4 v[NY][NX];
    #pragma unroll
    for (int iy = 0; iy < NY; ++iy) {
        const int r  = y + DY0 + iy;
        const int rs = ((unsigned)r < HOUT) ? r : y;     // safe addr; cf=0 later
        const float* vrow = vb + (size_t)(rs * HOUT) * CC;
        #pragma unroll
        for (int ix = 0; ix < NX; ++ix) {
            const int cpos = x + DX0 + ix;
            const int cs   = ((unsigned)cpos < HOUT) ? cpos : x;
            v[iy][ix] = *(const float4*)(vrow + (size_t)cs * CC);
        }
    }

    // ---- Phase 2: coefficients from attn (scalar loads, hide under vv). ----
    float cf[NY][NX];
    #pragma unroll
    for (int iy = 0; iy < NY; ++iy)
        #pragma unroll
        for (int ix = 0; ix < NX; ++ix)
            cf[iy][ix] = 0.f;

    const int ypad = y + 1, xpad = x + 1;
    if constexpr (YE) {
        if constexpr (XE) {
            addTap<2, 2, DY0, DX0>(cf, ab, ypad, xpad);
            if (x <= 25) addTap<2, 0, DY0, DX0>(cf, ab, ypad, xpad);
            if (y <= 25) {
                addTap<0, 2, DY0, DX0>(cf, ab, ypad, xpad);
                if (x <= 25) addTap<0, 0, DY0, DX0>(cf, ab, ypad, xpad);
            }
        } else {
            addTap<2, 1, DY0, DX0>(cf, ab, ypad, xpad);
            if (y <= 25) addTap<0, 1, DY0, DX0>(cf, ab, ypad, xpad);
        }
    } else {
        if constexpr (XE) {
            addTap<1, 2, DY0, DX0>(cf, ab, ypad, xpad);
            if (x <= 25) addTap<1, 0, DY0, DX0>(cf, ab, ypad, xpad);
        } else {
            addTap<1, 1, DY0, DX0>(cf, ab, ypad, xpad);
        }
    }

    // Zero coefficients of out-of-image taps (vv zero-padding semantics).
    #pragma unroll
    for (int iy = 0; iy < NY; ++iy) {
        const bool rv = (unsigned)(y + DY0 + iy) < HOUT;
        #pragma unroll
        for (int ix = 0; ix < NX; ++ix) {
            const bool cv = (unsigned)(x + DX0 + ix) < HOUT;
            cf[iy][ix] = (rv && cv) ? cf[iy][ix] : 0.f;
        }
    }

    // ---- Phase 3: FMA taps into 4-channel accumulator. ----
    float a0 = 0.f, a1 = 0.f, a2 = 0.f, a3 = 0.f;
    #pragma unroll
    for (int iy = 0; iy < NY; ++iy)
        #pragma unroll
        for (int ix = 0; ix < NX; ++ix) {
            const float  a = cf[iy][ix];
            const float4 u = v[iy][ix];
            a0 = fmaf(a, u.x, a0);
            a1 = fmaf(a, u.y, a1);
            a2 = fmaf(a, u.z, a2);
            a3 = fmaf(a, u.w, a3);
        }

    float4 o; o.x = a0; o.y = a1; o.z = a2; o.w = a3;
    return o;
}

__global__ __launch_bounds__(192)
void UnfoldMatmulFold_kernel(const float* __restrict__ vv,
                             const float* __restrict__ attn,
                             float* __restrict__ out)
{
    // XCD-aware swizzle (kept from R3): (id & 7) == (b & 7) so one image's
    // working set stays resident in a single XCD's L2.
    const unsigned id   = blockIdx.x;
    const unsigned xcd  = id & 7u;
    const unsigned j    = id >> 3;
    const unsigned bgrp = j / NPIX;
    const unsigned pix  = j - bgrp * NPIX;
    const int b = (int)((bgrp << 3) | xcd);
    const int y = (int)(pix / HOUT);
    const int x = (int)(pix - (unsigned)y * HOUT);

    const int tid = threadIdx.x;     // 0..191
    const int c4  = tid << 2;        // 4 channels per thread
    const int n   = tid >> 4;        // head (64 ch = 16 threads per head)

    const float* vb = vv   + (size_t)b * (NPIX * CC) + c4;
    const float* ab = attn + (size_t)b * (HH * HH * NHEADS * 81) + n * 81;

    float4 o;
    const bool ye = (y & 1) != 0;    // ypad = y+1 even
    const bool xe = (x & 1) != 0;
    if (ye) {
        if (xe) o = process<true,  true >(vb, ab, y, x);
        else    o = process<true,  false>(vb, ab, y, x);
    } else {
        if (xe) o = process<false, true >(vb, ab, y, x);
        else    o = process<false, false>(vb, ab, y, x);
    }

    const size_t oidx = (((size_t)b * HOUT + y) * HOUT + x) * CC + c4;
    *(float4*)&out[oidx] = o;
}

extern "C" void kernel_launch(void* const* d_in, const int* in_sizes, int n_in,
                              void* d_out, int out_size, void* d_ws, size_t ws_size,
                              hipStream_t stream) {
    const float* vv   = (const float*)d_in[0];
    const float* attn = (const float*)d_in[1];
    float* out        = (float*)d_out;

    const int B = in_sizes[0] / (NPIX * CC);   // in_sizes = ELEMENTS -> 64
    dim3 grid((unsigned)(B * NPIX));           // 50176 blocks, 1-D swizzled
    UnfoldMatmulFold_kernel<<<grid, 192, 0, stream>>>(vv, attn, out);
}

// Round 3
// 338.586 us; speedup vs baseline: 1.3792x; 1.1763x over previous
//
#include <hip/hip_runtime.h>
#include <stdint.h>

// Problem: KS=3, ST=2, PAD=1, H=W=28, C=768, NH=12, hh=ww=14, dh=64.
//
// R6: R5 counters showed OccupancyPercent=27.7% with VGPR=80 (no resource
// limit) and both pipes idle -> DISPATCH-STARVED: 3-wave blocks lived 3.2us
// and retired at 239 blocks/us, exactly the CP feed rate. Fix: one block
// computes a 2x2 output-pixel quad (y0=2*qy, x0=2*qx):
//   - 4x fewer blocks (12544), 4x per-thread work
//   - the 4 pixels share ONE 5x5 vv tap window (rows y0-1..y0+3, cols
//     x0-1..x0+3): 25 float4 loads vs 64 per-pixel (2.56x fewer)
//   - the contributing (kh,kw) combos become 9 fixed attn runs at
//     (h,w) in {qy,qy+1}x{qx,qx+1} with compile-time p and tap offsets:
//       P(0,0): p=4@(qy,qx)
//       P(0,1): p=5@(qy,qx); p=3@(qy,qx+1) if qx<13
//       P(1,0): p=7@(qy,qx); p=1@(qy+1,qx) if qy<13
//       P(1,1): p=8@(qy,qx); p=6@(qy,qx+1) if qx<13;
//               p=2@(qy+1,qx) if qy<13; p=0@(qy+1,qx+1) if both
//     (tap index i = PY-KH+qh+1, j = PX-KW+qw+1 -> IO,JO in {0,2})
//   - vv zero-padding handled by zeroing OOB taps once (block-uniform).
// Direct per-combo FMA (324 FMA/thread) beats a merged coefficient grid
// (337 ops) and needs no cf registers. All indexing compile-time.
#define HOUT 28
#define HH   14
#define NHEADS 12
#define CC   768
#define NPIX (HOUT * HOUT)   // 784
#define NQ   (HH * HH)       // 196 quads per image

// acc += sum_{qh,qw} ap[3*qh+qw] * v[IO+qh][JO+qw]   (IO/JO compile-time)
template<int IO, int JO>
__device__ __forceinline__ void fma9(float4& acc,
                                     const float* __restrict__ ap,
                                     const float4 (&v)[5][5])
{
    #pragma unroll
    for (int qh = 0; qh < 3; ++qh)
        #pragma unroll
        for (int qw = 0; qw < 3; ++qw) {
            const float  a = ap[3 * qh + qw];
            const float4 u = v[IO + qh][JO + qw];
            acc.x = fmaf(a, u.x, acc.x);
            acc.y = fmaf(a, u.y, acc.y);
            acc.z = fmaf(a, u.z, acc.z);
            acc.w = fmaf(a, u.w, acc.w);
        }
}

__global__ __launch_bounds__(192)
void UnfoldMatmulFold_kernel(const float* __restrict__ vv,
                             const float* __restrict__ attn,
                             float* __restrict__ out)
{
    // XCD-aware swizzle: (id & 7) == (b & 7) keeps one image's working set
    // resident in a single XCD's L2 (heuristic only).
    const unsigned id   = blockIdx.x;
    const unsigned xcd  = id & 7u;
    const unsigned j    = id >> 3;
    const unsigned bgrp = j / NQ;          // 0..7
    const unsigned q    = j - bgrp * NQ;   // 0..195
    const int b  = (int)((bgrp << 3) | xcd);
    const int qy = (int)(q / HH);
    const int qx = (int)(q - (unsigned)qy * HH);
    const int y0 = qy << 1;
    const int x0 = qx << 1;

    const int tid = threadIdx.x;     // 0..191
    const int c4  = tid << 2;        // 4 channels per thread
    const int n   = tid >> 4;        // head (64 ch = 16 threads per head)

    const float* vb = vv + (size_t)b * (NPIX * CC) + c4;

    // ---- Phase 1: 5x5 tap window, all 25 float4 loads issued up front. ----
    float4 v[5][5];
    #pragma unroll
    for (int i = 0; i < 5; ++i) {
        const int r  = y0 - 1 + i;
        const int rs = ((unsigned)r < HOUT) ? r : y0;     // safe addr
        const float* vrow = vb + (size_t)(rs * HOUT) * CC;
        #pragma unroll
        for (int jj = 0; jj < 5; ++jj) {
            const int cpos = x0 - 1 + jj;
            const int cs   = ((unsigned)cpos < HOUT) ? cpos : x0;
            v[i][jj] = *(const float4*)(vrow + (size_t)cs * CC);
        }
    }

    // Zero OOB taps (vv zero-padding). Conditions are block-uniform.
    #pragma unroll
    for (int i = 0; i < 5; ++i) {
        const bool rv = (unsigned)(y0 - 1 + i) < HOUT;
        #pragma unroll
        for (int jj = 0; jj < 5; ++jj) {
            const bool cv = (unsigned)(x0 - 1 + jj) < HOUT;
            if (!(rv && cv)) {
                v[i][jj].x = 0.f; v[i][jj].y = 0.f;
                v[i][jj].z = 0.f; v[i][jj].w = 0.f;
            }
        }
    }

    // ---- Phase 2: the 9 attn runs (contiguous 9 floats each). ----
    const float* ab = attn + (size_t)b * (NQ * NHEADS * 81) + n * 81;
    const size_t hw00 = (size_t)(qy * HH + qx) * (NHEADS * 81);
    const float* a00 = ab + hw00;                                  // (qy,  qx  )
    const float* a01 = ab + hw00 + (size_t)(NHEADS * 81);          // (qy,  qx+1)
    const float* a10 = ab + hw00 + (size_t)(HH * NHEADS * 81);     // (qy+1,qx  )
    const float* a11 = ab + hw00 + (size_t)((HH + 1) * NHEADS * 81);

    const bool hasX = (qx < 13);
    const bool hasY = (qy < 13);

    const size_t ob = (((size_t)b * HOUT + y0) * HOUT + x0) * CC + c4;
    float4 acc;

    // P(0,0): y even, x even -> kh=kw=1 only.
    acc.x = acc.y = acc.z = acc.w = 0.f;
    fma9<0, 0>(acc, a00 + 4 * 9, v);
    *(float4*)&out[ob] = acc;

    // P(0,1): kh=1; kw=2@(qy,qx), kw=0@(qy,qx+1).
    acc.x = acc.y = acc.z = acc.w = 0.f;
    fma9<0, 0>(acc, a00 + 5 * 9, v);
    if (hasX) fma9<0, 2>(acc, a01 + 3 * 9, v);
    *(float4*)&out[ob + CC] = acc;

    // P(1,0): kw=1; kh=2@(qy,qx), kh=0@(qy+1,qx).
    acc.x = acc.y = acc.z = acc.w = 0.f;
    fma9<0, 0>(acc, a00 + 7 * 9, v);
    if (hasY) fma9<2, 0>(acc, a10 + 1 * 9, v);
    *(float4*)&out[ob + HOUT * CC] = acc;

    // P(1,1): kh,kw in {0,2}.
    acc.x = acc.y = acc.z = acc.w = 0.f;
    fma9<0, 0>(acc, a00 + 8 * 9, v);
    if (hasX) fma9<0, 2>(acc, a01 + 6 * 9, v);
    if (hasY) fma9<2, 0>(acc, a10 + 2 * 9, v);
    if (hasX && hasY) fma9<2, 2>(acc, a11 + 0 * 9, v);
    *(float4*)&out[ob + (HOUT + 1) * CC] = acc;
}

extern "C" void kernel_launch(void* const* d_in, const int* in_sizes, int n_in,
                              void* d_out, int out_size, void* d_ws, size_t ws_size,
                              hipStream_t stream) {
    const float* vv   = (const float*)d_in[0];
    const float* attn = (const float*)d_in[1];
    float* out        = (float*)d_out;

    const int B = in_sizes[0] / (NPIX * CC);   // in_sizes = ELEMENTS -> 64
    dim3 grid((unsigned)(B * NQ));             // 12544 blocks, 1-D swizzled
    UnfoldMatmulFold_kernel<<<grid, 192, 0, stream>>>(vv, attn, out);
}